// Round 7
// baseline (163.304 us; speedup 1.0000x reference)
//
#include <hip/hip_runtime.h>
#include <hip/hip_bf16.h>
#include <cstddef>

// ---------------- problem constants ----------------
#define BB   8
#define HH   120
#define WW   160
#define HW   19200          // HH*WW
#define NPIX 153600         // BB*HW
#define CORC 196

#define AS_  ((float)(6.0/127.0))   // ACT_SCALE
#define FS_  0.03125f               // FLOW_SCALE = 3.96875/127 = 2^-5 exactly

// ws layout:
//   float[0]=sd, float[1]=sp, float[2]=s_c1
//   ushort[32 .. 32+21504)      : convc1 B-frags (bf16 int codes)
//   float[OFF_WF1 .. +128)      : Wf1 dequant
//   float[OFF_WF2 .. +2048)     : Wf2 dequant transposed
//   float[OFF_WD  .. +1152)     : Wd integer codes
//   ushort[OFF_WPQ_US .. +10240): Wp B-frags (bf16 int codes)
#define OFF_WF1 18832
#define OFF_WF2 18960
#define OFF_WD  21008
#define OFF_WPQ_US 44320
#define CFQ_BYTE_OFF 131072         // int8 activation buffer, 8*128*19200 bytes

typedef __attribute__((ext_vector_type(8)))  short short8;
typedef __attribute__((ext_vector_type(4)))  float f32x4;
typedef unsigned int u32;

__device__ __forceinline__ float clip127(float x) {
    return fminf(fmaxf(x, -127.f), 127.f);
}

// round-to-nearest-even fp32 -> bf16 (finite inputs only)
__device__ __forceinline__ unsigned short f2bf(float x) {
    unsigned int u = __float_as_uint(x);
    unsigned int r = (u + 0x7fffu + ((u >> 16) & 1u)) >> 16;
    return (unsigned short)r;
}

// ---------------- kernel 0: weight fake-quant ----------------
__global__ __launch_bounds__(256) void quant_weights(
    const float* __restrict__ Wc1, const float* __restrict__ Wf1,
    const float* __restrict__ Wf2, const float* __restrict__ Wd,
    const float* __restrict__ Wp,  float* __restrict__ ws)
{
    __shared__ float red[256];
    const int t = blockIdx.x;
    const float* src = (t == 0) ? Wc1 : (t == 1) ? Wf1 : (t == 2) ? Wf2 : (t == 3) ? Wd : Wp;
    const int n = (t == 0) ? 18816 : (t == 1) ? 128 : (t == 2) ? 2048 : (t == 3) ? 1152 : 10240;
    const int tid = threadIdx.x;

    float m = 0.f;
    for (int i = tid; i < n; i += 256) m = fmaxf(m, fabsf(src[i]));
    red[tid] = m;
    __syncthreads();
    for (int s = 128; s > 0; s >>= 1) {
        if (tid < s) red[tid] = fmaxf(red[tid], red[tid + s]);
        __syncthreads();
    }
    const float s = red[0] / 127.0f + 1e-12f;

    if (t == 0) {
        // convc1 weights as MFMA B-frags: o = nt*16+(l&15), k = kt*32+((l>>4)<<3)+e
        unsigned short* bf = (unsigned short*)ws + 32;
        for (int j = tid; j < 21504; j += 256) {
            const int e    = j & 7;
            const int l    = (j >> 3) & 63;
            const int tile = j >> 9;
            const int nt   = tile % 6;
            const int kt   = tile / 6;
            const int out  = nt * 16 + (l & 15);
            const int k    = kt * 32 + ((l >> 4) << 3) + e;
            float q = 0.f;
            if (k < 196) q = clip127(rintf(Wc1[out * 196 + k] / s));
            bf[j] = f2bf(q);
        }
        if (tid == 0) ws[2] = s;
    } else if (t == 4) {
        // pointwise weights as MFMA B-frags: 5 n-tiles x 4 k-steps
        unsigned short* bf = (unsigned short*)ws + OFF_WPQ_US;
        for (int j = tid; j < 10240; j += 256) {
            const int e    = j & 7;
            const int l    = (j >> 3) & 63;
            const int tile = j >> 9;     // 0..19
            const int nt   = tile % 5;
            const int kt   = tile / 5;
            const int o    = nt * 16 + (l & 15);
            const int k    = kt * 32 + ((l >> 4) << 3) + e;
            const float q  = clip127(rintf(Wp[o * 128 + k] / s));
            bf[j] = f2bf(q);
        }
        if (tid == 0) ws[1] = s;
    } else {
        for (int i = tid; i < n; i += 256) {
            const float q = clip127(rintf(src[i] / s));
            if (t == 1) {            // Wf1 [64][2]
                ws[OFF_WF1 + i] = s * q;
            } else if (t == 2) {     // Wf2 [32][64] -> transposed [64][32]
                int o = i / 64, c = i % 64;
                ws[OFF_WF2 + c * 32 + o] = s * q;
            } else {                 // Wd [128][9]: keep integer q
                ws[OFF_WD + i] = q;
            }
        }
        if (tid == 0 && t == 3) ws[0] = s;
    }
}

// ---------------- kernel 1a: convc1 (196 -> 96), MFMA + global_load_lds dbuf ----
// 128 pixels/block, 4 waves. Per kt-step: DMA-stage the next 32ch x 128pix fp32
// slab into LDS (no VGPR cost), ds_read fragments, hi/lo bf16 split, 24 MFMA.
// LDS: two 16KB slabs double-buffered; t8 transpose buffer unioned on slab A.
#define TSTRIDE 136   // t8 row stride (bytes)
__global__ __launch_bounds__(256, 3) void k1_convc1(
    const float* __restrict__ corr, const float* __restrict__ bc1,
    const float* __restrict__ ws,   signed char* __restrict__ cfq)
{
    __shared__ __align__(1024) char smem[32768];   // [2][32ch][128pix] fp32 / t8 union

    const int tid = threadIdx.x;
    const int w   = tid >> 6;
    const int l   = tid & 63;
    const int p0  = blockIdx.x * 128;          // 19200 % 128 == 0 -> no batch straddle
    const int b   = p0 / HW;
    const int hw0 = p0 % HW;
    const float* cp = corr + (size_t)b * CORC * HW + hw0;

    const short8* Bfr = (const short8*)((const unsigned short*)ws + 32);

    // DMA stage: wave w stages local channels w*8..w*8+7 of K-step kt into slab `base`.
    // Each instr: 2 channels (lanes 0-31 -> ch, 32-63 -> ch+1), lane writes base+cl*512+l*16.
    // Channels >= 196 clamp to 195: finite garbage x zero B-frag = exact 0.
#define STAGE(KT, BASE)                                                               \
    {   _Pragma("unroll")                                                             \
        for (int i = 0; i < 4; ++i) {                                                 \
            const int cl = w * 8 + i * 2;                                             \
            int ch = (KT) * 32 + cl + (l >> 5);                                       \
            ch = ch < CORC ? ch : (CORC - 1);                                         \
            const char* src = (const char*)cp + (size_t)ch * (HW * 4) + ((l & 31) * 16); \
            u32* dst = (u32*)(smem + (BASE) + cl * 512);                              \
            __builtin_amdgcn_global_load_lds(                                         \
                (const __attribute__((address_space(1))) u32*)src,                    \
                (__attribute__((address_space(3))) u32*)dst, 16, 0, 0);               \
        }                                                                             }

    f32x4 a00 = {0.f,0.f,0.f,0.f}, a01 = a00, a02 = a00, a03 = a00, a04 = a00, a05 = a00;
    f32x4 a10 = a00, a11 = a00, a12 = a00, a13 = a00, a14 = a00, a15 = a00;

    STAGE(0, 0)
    STAGE(1, 16384)
    __syncthreads();

    const int pixoff = (w * 32 + (l & 15)) * 4;   // tile-0 pixel byte offset
    const int chbase = (l >> 4) << 3;             // fragment k sub-channel base

    for (int kt = 0; kt < 7; ++kt) {
        const int base = (kt & 1) << 14;

        // B-frags for this K-step (L2-resident; latency overlaps ds_read+convert)
        const short8 b0 = Bfr[(kt * 6 + 0) * 64 + l];
        const short8 b1 = Bfr[(kt * 6 + 1) * 64 + l];
        const short8 b2 = Bfr[(kt * 6 + 2) * 64 + l];
        const short8 b3 = Bfr[(kt * 6 + 3) * 64 + l];
        const short8 b4 = Bfr[(kt * 6 + 4) * 64 + l];
        const short8 b5 = Bfr[(kt * 6 + 5) * 64 + l];

        short8 h0_, l0_, h1_, l1_;
#pragma unroll
        for (int e = 0; e < 8; ++e) {
            const char* ap = smem + base + (chbase + e) * 512 + pixoff;
            const float v0 = *(const float*)ap;
            const float v1 = *(const float*)(ap + 64);
            const unsigned short h0 = f2bf(v0);
            const unsigned short h1 = f2bf(v1);
            h0_[e] = (short)h0; h1_[e] = (short)h1;
            l0_[e] = (short)f2bf(v0 - __uint_as_float((unsigned int)h0 << 16));
            l1_[e] = (short)f2bf(v1 - __uint_as_float((unsigned int)h1 << 16));
        }

#define MF(BB_, A0, A1)                                                          \
        A0 = __builtin_amdgcn_mfma_f32_16x16x32_bf16(l0_, BB_, A0, 0, 0, 0);     \
        A0 = __builtin_amdgcn_mfma_f32_16x16x32_bf16(h0_, BB_, A0, 0, 0, 0);     \
        A1 = __builtin_amdgcn_mfma_f32_16x16x32_bf16(l1_, BB_, A1, 0, 0, 0);     \
        A1 = __builtin_amdgcn_mfma_f32_16x16x32_bf16(h1_, BB_, A1, 0, 0, 0);
        MF(b0, a00, a10) MF(b1, a01, a11) MF(b2, a02, a12)
        MF(b3, a03, a13) MF(b4, a04, a14) MF(b5, a05, a15)
#undef MF

        __syncthreads();                          // all waves done with `base`
        if (kt < 5) STAGE(kt + 2, base)           // refill it for kt+2
    }
#undef STAGE

    // ---- epilogue: quant chain -> t8 transpose buffer (aliases slab A) ----
    const float sc1 = ws[2];
    signed char* t8 = (signed char*)smem;

#define EPI(ACC, NT, TILE)                                                        \
    {   const int out = (NT) * 16 + (l & 15);                                     \
        const float bias = bc1[out];                                              \
        _Pragma("unroll")                                                         \
        for (int i = 0; i < 4; ++i) {                                             \
            const int prow = w * 32 + (TILE) * 16 + ((l >> 4) << 2) + i;          \
            float v  = fmaf(sc1, ACC[i], bias);                                   \
            float aq = AS_ * clip127(rintf(v / AS_));                             \
            float r  = fmaxf(aq, 0.f);                                            \
            float kk = fminf(rintf(r * 32.f), 127.f);                             \
            float cf = kk * FS_;                                                  \
            float q8 = clip127(rintf(cf / AS_));                                  \
            t8[out * TSTRIDE + prow] = (signed char)(int)q8;                      \
        }                                                                         }
    EPI(a00, 0, 0) EPI(a01, 1, 0) EPI(a02, 2, 0) EPI(a03, 3, 0) EPI(a04, 4, 0) EPI(a05, 5, 0)
    EPI(a10, 0, 1) EPI(a11, 1, 1) EPI(a12, 2, 1) EPI(a13, 3, 1) EPI(a14, 4, 1) EPI(a15, 5, 1)
#undef EPI
    __syncthreads();

    // ---- coalesced store: 96 rows x 128 bytes ----
#pragma unroll
    for (int r = 0; r < 12; ++r) {
        const int d   = r * 256 + tid;     // 3072 dwords total
        const int out = d >> 5;
        const int pd  = d & 31;
        const unsigned int v = *(const unsigned int*)(t8 + out * TSTRIDE + pd * 4);
        *(unsigned int*)(cfq + (size_t)(b * 128 + out) * HW + hw0 + pd * 4) = v;
    }
}

// ---------------- kernel 1b: flo path (convf1 2->64, convf2 64->32) ----------------
typedef __attribute__((ext_vector_type(16))) float f32x16;
__global__ __launch_bounds__(256) void k1_flo(
    const float* __restrict__ flow, const float* __restrict__ bf1,
    const float* __restrict__ bf2,  const float* __restrict__ ws,
    signed char* __restrict__ cfq)
{
    const int p  = blockIdx.x * 256 + threadIdx.x;
    const int b  = p / HW;
    const int hw = p % HW;

    const float f0 = flow[(size_t)(b * 2) * HW + hw];
    const float f1 = flow[(size_t)(b * 2 + 1) * HW + hw];

    f32x16 a2a, a2b;
#pragma unroll
    for (int j = 0; j < 16; ++j) { a2a[j] = 0.f; a2b[j] = 0.f; }

    for (int c = 0; c < 64; ++c) {
        const float w0 = ws[OFF_WF1 + 2 * c];
        const float w1 = ws[OFF_WF1 + 2 * c + 1];
        float v  = fmaf(f0, w0, fmaf(f1, w1, bf1[c]));
        float r  = fmaxf(v, 0.f);
        float af = AS_ * fminf(rintf(r / AS_), 127.f);
        const float* w2 = ws + OFF_WF2 + c * 32;
#pragma unroll
        for (int j = 0; j < 16; ++j) {
            a2a[j] = fmaf(af, w2[j],      a2a[j]);
            a2b[j] = fmaf(af, w2[16 + j], a2b[j]);
        }
    }

    signed char* op = cfq + (size_t)b * 128 * HW + (size_t)96 * HW + hw;
#define FLOEPI(ACC, BASE)                                                        \
    _Pragma("unroll")                                                            \
    for (int j = 0; j < 16; ++j) {                                               \
        const int o = (BASE) + j;                                                \
        float v  = ACC[j] + bf2[o];                                              \
        float aq = AS_ * clip127(rintf(v / AS_));                                \
        float r  = fmaxf(aq, 0.f);                                               \
        float kk = fminf(rintf(r * 32.f), 127.f);                                \
        float cf = kk * FS_;                                                     \
        float q8 = clip127(rintf(cf / AS_));                                     \
        op[(size_t)o * HW] = (signed char)(int)q8;                               \
    }
    FLOEPI(a2a, 0) FLOEPI(a2b, 16)
#undef FLOEPI
}

// ---------------- kernel 2: depthwise 3x3 (VALU, exact) + pointwise via MFMA ----------------
#define STG_STRIDE 44
__global__ __launch_bounds__(256) void k2_dwpw(
    const float* __restrict__ flow, const float* __restrict__ bd,
    const float* __restrict__ bp,   const float* __restrict__ ws,
    const signed char* __restrict__ cfq, float* __restrict__ out)
{
    __shared__ signed char stage[4 * 128 * STG_STRIDE];   // [row][c][44]
    __shared__ unsigned short afrag[64 * 136];            // [pix][136] bf16 codes

    const int tid = threadIdx.x;
    const int bid = blockIdx.x;
    const int b   = bid / 300;          // 60 row-tiles * 5 col-tiles
    const int rem = bid % 300;
    const int h0  = (rem / 5) * 2;
    const int w0  = (rem % 5) * 32;

    for (int j = tid; j < 5120; j += 256) {
        const int i   = j % 10;
        const int c   = (j / 10) % 128;
        const int row = j / 1280;
        const int h   = h0 - 1 + row;
        const int wb  = w0 - 4 + 4 * i;
        unsigned int v = 0u;
        if (h >= 0 && h < HH && wb >= 0 && wb <= WW - 4)
            v = *(const unsigned int*)(cfq + ((size_t)(b * 128 + c) * HW + (size_t)h * WW + wb));
        *(unsigned int*)(stage + (row * 128 + c) * STG_STRIDE + i * 4) = v;
    }
    __syncthreads();

    const int c0 = tid & 63;
    const int pg = tid >> 6;
    const float sd = ws[0], sp = ws[1];
    const float ASsd = AS_ * sd;

    float wd0[9], wd1[9];
#pragma unroll
    for (int t9 = 0; t9 < 9; ++t9) {
        wd0[t9] = ws[OFF_WD + c0 * 9 + t9];
        wd1[t9] = ws[OFF_WD + (c0 + 64) * 9 + t9];
    }
    const float bd0 = bd[c0], bd1 = bd[c0 + 64];

#pragma unroll
    for (int pp = 0; pp < 16; ++pp) {
        const int pix = pg * 16 + pp;
        const int r   = pix >> 5;
        const int col = pix & 31;
        float s0 = 0.f, s1 = 0.f;
#pragma unroll
        for (int dy = 0; dy < 3; ++dy) {
            const int rb = (r + dy) * 128;
            const int xb = 3 + col;
#pragma unroll
            for (int dd = 0; dd < 3; ++dd) {
                s0 = fmaf((float)stage[(rb + c0     ) * STG_STRIDE + xb + dd], wd0[dy * 3 + dd], s0);
                s1 = fmaf((float)stage[(rb + c0 + 64) * STG_STRIDE + xb + dd], wd1[dy * 3 + dd], s1);
            }
        }
        const float q0 = clip127(rintf(fmaf(ASsd, s0, bd0) / AS_));
        const float q1 = clip127(rintf(fmaf(ASsd, s1, bd1) / AS_));
        afrag[pix * 136 + c0]      = f2bf(q0);
        afrag[pix * 136 + c0 + 64] = f2bf(q1);
    }
    __syncthreads();

    const int wv = tid >> 6;
    const int l  = tid & 63;
    const unsigned short* A = afrag + (size_t)(wv * 16 + (l & 15)) * 136 + ((l >> 4) << 3);
    const short8* Bfr = (const short8*)((const unsigned short*)ws + OFF_WPQ_US);

    f32x4 pc0 = {0.f,0.f,0.f,0.f}, pc1 = pc0, pc2 = pc0, pc3 = pc0, pc4 = pc0;

#define PTSTEP(ACC, KT, NT)                                                      \
    {   short8 bq = Bfr[((KT) * 5 + (NT)) * 64 + l];                             \
        ACC = __builtin_amdgcn_mfma_f32_16x16x32_bf16(a_, bq, ACC, 0, 0, 0);     }
#pragma unroll
    for (int kt = 0; kt < 4; ++kt) {
        short8 a_ = *(const short8*)(A + kt * 32);
        PTSTEP(pc0, kt, 0) PTSTEP(pc1, kt, 1) PTSTEP(pc2, kt, 2)
        PTSTEP(pc3, kt, 3) PTSTEP(pc4, kt, 4)
    }
#undef PTSTEP

    const float ASsp = AS_ * sp;
    float* ob = out + (size_t)b * 82 * HW;

#define PEPI(ACC, NT)                                                            \
    {   const int o = (NT) * 16 + (l & 15);                                      \
        const float bias = bp[o];                                                \
        _Pragma("unroll")                                                        \
        for (int i = 0; i < 4; ++i) {                                            \
            const int pix = wv * 16 + ((l >> 4) << 2) + i;                       \
            const int hw  = (h0 + (pix >> 5)) * WW + w0 + (pix & 31);            \
            float v = fmaf(ASsp, ACC[i], bias);                                  \
            float r = fmaxf(v, 0.f);                                             \
            float k = fminf(rintf(r * 32.f), 127.f);                             \
            ob[(size_t)o * HW + hw] = k * FS_;                                   \
        }                                                                        }
    PEPI(pc0, 0) PEPI(pc1, 1) PEPI(pc2, 2) PEPI(pc3, 3) PEPI(pc4, 4)
#undef PEPI

    if (tid < 128) {
        const int ch  = tid >> 6;
        const int pix = tid & 63;
        const int hw  = (h0 + (pix >> 5)) * WW + w0 + (pix & 31);
        const float f = flow[(size_t)(b * 2 + ch) * HW + hw];
        const float k = clip127(rintf(f * 32.f));
        ob[(size_t)(80 + ch) * HW + hw] = k * FS_;
    }
}

// ---------------- launcher ----------------
extern "C" void kernel_launch(void* const* d_in, const int* in_sizes, int n_in,
                              void* d_out, int out_size, void* d_ws, size_t ws_size,
                              hipStream_t stream) {
    const float* flow = (const float*)d_in[0];
    const float* corr = (const float*)d_in[1];
    const float* Wc1  = (const float*)d_in[2];
    const float* bc1  = (const float*)d_in[3];
    const float* Wf1  = (const float*)d_in[4];
    const float* bf1  = (const float*)d_in[5];
    const float* Wf2  = (const float*)d_in[6];
    const float* bf2  = (const float*)d_in[7];
    const float* Wd   = (const float*)d_in[8];
    const float* bd   = (const float*)d_in[9];
    const float* Wp   = (const float*)d_in[10];
    const float* bp   = (const float*)d_in[11];

    float* ws = (float*)d_ws;
    signed char* cfq = (signed char*)d_ws + CFQ_BYTE_OFF;
    float* out = (float*)d_out;

    quant_weights<<<5, 256, 0, stream>>>(Wc1, Wf1, Wf2, Wd, Wp, ws);
    k1_convc1<<<NPIX / 128, 256, 0, stream>>>(corr, bc1, ws, cfq);
    k1_flo<<<NPIX / 256, 256, 0, stream>>>(flow, bf1, bf2, ws, cfq);
    k2_dwpw<<<2400, 256, 0, stream>>>(flow, bd, bp, ws, cfq, out);
}

// Round 9
// 158.670 us; speedup vs baseline: 1.0292x; 1.0292x over previous
//
#include <hip/hip_runtime.h>
#include <hip/hip_bf16.h>
#include <cstddef>

// ---------------- problem constants ----------------
#define BB   8
#define HH   120
#define WW   160
#define HW   19200          // HH*WW
#define NPIX 153600         // BB*HW
#define CORC 196

#define AS_  ((float)(6.0/127.0))   // ACT_SCALE
#define FS_  0.03125f               // FLOW_SCALE = 3.96875/127 = 2^-5 exactly

// ws layout:
//   float[0]=sd, float[1]=sp, float[2]=s_c1
//   ushort[32 .. 32+21504)      : convc1 B-frags (bf16 int codes)
//   float[OFF_WF1 .. +128)      : Wf1 dequant
//   float[OFF_WF2 .. +2048)     : Wf2 dequant transposed
//   float[OFF_WD  .. +1152)     : Wd integer codes
//   ushort[OFF_WPQ_US .. +10240): Wp B-frags (bf16 int codes)
#define OFF_WF1 18832
#define OFF_WF2 18960
#define OFF_WD  21008
#define OFF_WPQ_US 44320
#define CFQ_BYTE_OFF 131072         // int8 activation buffer, 8*128*19200 bytes

typedef __attribute__((ext_vector_type(8)))  short short8;
typedef __attribute__((ext_vector_type(4)))  float f32x4;
typedef unsigned int u32;

__device__ __forceinline__ float clip127(float x) {
    return fminf(fmaxf(x, -127.f), 127.f);
}

// round-to-nearest-even fp32 -> bf16 (finite inputs only)
__device__ __forceinline__ unsigned short f2bf(float x) {
    unsigned int u = __float_as_uint(x);
    unsigned int r = (u + 0x7fffu + ((u >> 16) & 1u)) >> 16;
    return (unsigned short)r;
}

// ---------------- kernel 0: weight fake-quant ----------------
__global__ __launch_bounds__(256) void quant_weights(
    const float* __restrict__ Wc1, const float* __restrict__ Wf1,
    const float* __restrict__ Wf2, const float* __restrict__ Wd,
    const float* __restrict__ Wp,  float* __restrict__ ws)
{
    __shared__ float red[256];
    const int t = blockIdx.x;
    const float* src = (t == 0) ? Wc1 : (t == 1) ? Wf1 : (t == 2) ? Wf2 : (t == 3) ? Wd : Wp;
    const int n = (t == 0) ? 18816 : (t == 1) ? 128 : (t == 2) ? 2048 : (t == 3) ? 1152 : 10240;
    const int tid = threadIdx.x;

    float m = 0.f;
    for (int i = tid; i < n; i += 256) m = fmaxf(m, fabsf(src[i]));
    red[tid] = m;
    __syncthreads();
    for (int s = 128; s > 0; s >>= 1) {
        if (tid < s) red[tid] = fmaxf(red[tid], red[tid + s]);
        __syncthreads();
    }
    const float s = red[0] / 127.0f + 1e-12f;

    if (t == 0) {
        // convc1 weights as MFMA B-frags: o = nt*16+(l&15), k = kt*32+((l>>4)<<3)+e
        unsigned short* bf = (unsigned short*)ws + 32;
        for (int j = tid; j < 21504; j += 256) {
            const int e    = j & 7;
            const int l    = (j >> 3) & 63;
            const int tile = j >> 9;
            const int nt   = tile % 6;
            const int kt   = tile / 6;
            const int out  = nt * 16 + (l & 15);
            const int k    = kt * 32 + ((l >> 4) << 3) + e;
            float q = 0.f;
            if (k < 196) q = clip127(rintf(Wc1[out * 196 + k] / s));
            bf[j] = f2bf(q);
        }
        if (tid == 0) ws[2] = s;
    } else if (t == 4) {
        // pointwise weights as MFMA B-frags: 5 n-tiles x 4 k-steps
        unsigned short* bf = (unsigned short*)ws + OFF_WPQ_US;
        for (int j = tid; j < 10240; j += 256) {
            const int e    = j & 7;
            const int l    = (j >> 3) & 63;
            const int tile = j >> 9;     // 0..19
            const int nt   = tile % 5;
            const int kt   = tile / 5;
            const int o    = nt * 16 + (l & 15);
            const int k    = kt * 32 + ((l >> 4) << 3) + e;
            const float q  = clip127(rintf(Wp[o * 128 + k] / s));
            bf[j] = f2bf(q);
        }
        if (tid == 0) ws[1] = s;
    } else {
        for (int i = tid; i < n; i += 256) {
            const float q = clip127(rintf(src[i] / s));
            if (t == 1) {            // Wf1 [64][2]
                ws[OFF_WF1 + i] = s * q;
            } else if (t == 2) {     // Wf2 [32][64] -> transposed [64][32]
                int o = i / 64, c = i % 64;
                ws[OFF_WF2 + c * 32 + o] = s * q;
            } else {                 // Wd [128][9]: keep integer q
                ws[OFF_WD + i] = q;
            }
        }
        if (tid == 0 && t == 3) ws[0] = s;
    }
}

// ---------------- kernel 1a: convc1 (196 -> 96) ----------------
// MFMA + global_load_lds double-buffer, counted waits (m201-style):
//   top of iter kt: s_waitcnt vmcnt(4)  -> own stage(kt) landed (4 loads/STAGE,
//                   stage(kt+1) still in flight), raw s_barrier.
//   after ds_reads: lgkmcnt(0) + s_barrier (slab free), issue b-frags FIRST,
//                   then STAGE(kt+2): compiler's minimal b-frag waits
//                   (vmcnt(9)..(4)) leave stage(kt+2) in flight across iters.
#define TSTRIDE 136   // t8 row stride (bytes)
__global__ __launch_bounds__(256, 3) void k1_convc1(
    const float* __restrict__ corr, const float* __restrict__ bc1,
    const float* __restrict__ ws,   signed char* __restrict__ cfq)
{
    __shared__ __align__(1024) char smem[32768];   // [2][32ch][128pix] fp32 / t8 union

    const int tid = threadIdx.x;
    const int w   = tid >> 6;
    const int l   = tid & 63;
    const int p0  = blockIdx.x * 128;          // 19200 % 128 == 0 -> no batch straddle
    const int b   = p0 / HW;
    const int hw0 = p0 % HW;
    const float* cp = corr + (size_t)b * CORC * HW + hw0;

    const short8* Bfr = (const short8*)((const unsigned short*)ws + 32);

    // DMA stage: wave w stages local channels w*8..w*8+7 of K-step kt into slab BASE.
    // 4 global_load_lds per wave; each covers 2 channels (lanes 0-31 / 32-63).
#define STAGE(KT, BASE)                                                               \
    {   _Pragma("unroll")                                                             \
        for (int i = 0; i < 4; ++i) {                                                 \
            const int cl = w * 8 + i * 2;                                             \
            int ch = (KT) * 32 + cl + (l >> 5);                                       \
            ch = ch < CORC ? ch : (CORC - 1);                                         \
            const char* src = (const char*)cp + (size_t)ch * (HW * 4) + ((l & 31) * 16); \
            u32* dst = (u32*)(smem + (BASE) + cl * 512);                              \
            __builtin_amdgcn_global_load_lds(                                         \
                (const __attribute__((address_space(1))) u32*)src,                    \
                (__attribute__((address_space(3))) u32*)dst, 16, 0, 0);               \
        }                                                                             }

    f32x4 a00 = {0.f,0.f,0.f,0.f}, a01 = a00, a02 = a00, a03 = a00, a04 = a00, a05 = a00;
    f32x4 a10 = a00, a11 = a00, a12 = a00, a13 = a00, a14 = a00, a15 = a00;

    STAGE(0, 0)
    STAGE(1, 16384)

    const int pixoff = (w * 32 + (l & 15)) * 4;   // tile-0 pixel byte offset
    const int chbase = (l >> 4) << 3;             // fragment k sub-channel base

#pragma unroll
    for (int kt = 0; kt < 7; ++kt) {
        const int base = (kt & 1) << 14;

        asm volatile("s_waitcnt vmcnt(4)" ::: "memory");   // own stage(kt) landed
        __builtin_amdgcn_sched_barrier(0);
        __builtin_amdgcn_s_barrier();                      // all waves: slab(kt) ready
        __builtin_amdgcn_sched_barrier(0);

        // ---- ds_read slab(kt) into registers ----
        float v0[8], v1[8];
#pragma unroll
        for (int e = 0; e < 8; ++e) {
            const char* ap = smem + base + (chbase + e) * 512 + pixoff;
            v0[e] = *(const float*)ap;
            v1[e] = *(const float*)(ap + 64);
        }
        __builtin_amdgcn_sched_barrier(0);
        asm volatile("s_waitcnt lgkmcnt(0)" ::: "memory");  // values in regs
        __builtin_amdgcn_sched_barrier(0);
        __builtin_amdgcn_s_barrier();                       // all waves done reading
        __builtin_amdgcn_sched_barrier(0);

        // ---- B-frags first (their minimal waits keep the new stage in flight) ----
        const short8 b0 = Bfr[(kt * 6 + 0) * 64 + l];
        const short8 b1 = Bfr[(kt * 6 + 1) * 64 + l];
        const short8 b2 = Bfr[(kt * 6 + 2) * 64 + l];
        const short8 b3 = Bfr[(kt * 6 + 3) * 64 + l];
        const short8 b4 = Bfr[(kt * 6 + 4) * 64 + l];
        const short8 b5 = Bfr[(kt * 6 + 5) * 64 + l];
        __builtin_amdgcn_sched_barrier(0);

        if (kt < 5) STAGE(kt + 2, base)            // refill just-freed slab
        __builtin_amdgcn_sched_barrier(0);

        // ---- RNE hi/lo bf16 split (round-7 math) ----
        short8 h0_, l0_, h1_, l1_;
#pragma unroll
        for (int e = 0; e < 8; ++e) {
            const float va = v0[e], vb = v1[e];
            const unsigned short ha = f2bf(va);
            const unsigned short hb = f2bf(vb);
            h0_[e] = (short)ha; h1_[e] = (short)hb;
            l0_[e] = (short)f2bf(va - __uint_as_float((unsigned int)ha << 16));
            l1_[e] = (short)f2bf(vb - __uint_as_float((unsigned int)hb << 16));
        }

#define MF(BB_, A0, A1)                                                          \
        A0 = __builtin_amdgcn_mfma_f32_16x16x32_bf16(l0_, BB_, A0, 0, 0, 0);     \
        A0 = __builtin_amdgcn_mfma_f32_16x16x32_bf16(h0_, BB_, A0, 0, 0, 0);     \
        A1 = __builtin_amdgcn_mfma_f32_16x16x32_bf16(l1_, BB_, A1, 0, 0, 0);     \
        A1 = __builtin_amdgcn_mfma_f32_16x16x32_bf16(h1_, BB_, A1, 0, 0, 0);
        MF(b0, a00, a10) MF(b1, a01, a11) MF(b2, a02, a12)
        MF(b3, a03, a13) MF(b4, a04, a14) MF(b5, a05, a15)
#undef MF
    }
#undef STAGE

    // ---- epilogue: quant chain -> t8 transpose buffer (aliases slab A; safe:
    // every wave passed the in-loop second barrier after its last slab read) ----
    const float sc1 = ws[2];
    signed char* t8 = (signed char*)smem;

#define EPI(ACC, NT, TILE)                                                        \
    {   const int out = (NT) * 16 + (l & 15);                                     \
        const float bias = bc1[out];                                              \
        _Pragma("unroll")                                                         \
        for (int i = 0; i < 4; ++i) {                                             \
            const int prow = w * 32 + (TILE) * 16 + ((l >> 4) << 2) + i;          \
            float v  = fmaf(sc1, ACC[i], bias);                                   \
            float aq = AS_ * clip127(rintf(v / AS_));                             \
            float r  = fmaxf(aq, 0.f);                                            \
            float kk = fminf(rintf(r * 32.f), 127.f);                             \
            float cf = kk * FS_;                                                  \
            float q8 = clip127(rintf(cf / AS_));                                  \
            t8[out * TSTRIDE + prow] = (signed char)(int)q8;                      \
        }                                                                         }
    EPI(a00, 0, 0) EPI(a01, 1, 0) EPI(a02, 2, 0) EPI(a03, 3, 0) EPI(a04, 4, 0) EPI(a05, 5, 0)
    EPI(a10, 0, 1) EPI(a11, 1, 1) EPI(a12, 2, 1) EPI(a13, 3, 1) EPI(a14, 4, 1) EPI(a15, 5, 1)
#undef EPI
    __syncthreads();

    // ---- coalesced store: 96 rows x 128 bytes ----
#pragma unroll
    for (int r = 0; r < 12; ++r) {
        const int d   = r * 256 + tid;     // 3072 dwords total
        const int out = d >> 5;
        const int pd  = d & 31;
        const unsigned int v = *(const unsigned int*)(t8 + out * TSTRIDE + pd * 4);
        *(unsigned int*)(cfq + (size_t)(b * 128 + out) * HW + hw0 + pd * 4) = v;
    }
}

// ---------------- kernel 1b: flo path (convf1 2->64, convf2 64->32) ----------------
typedef __attribute__((ext_vector_type(16))) float f32x16;
__global__ __launch_bounds__(256) void k1_flo(
    const float* __restrict__ flow, const float* __restrict__ bf1,
    const float* __restrict__ bf2,  const float* __restrict__ ws,
    signed char* __restrict__ cfq)
{
    const int p  = blockIdx.x * 256 + threadIdx.x;
    const int b  = p / HW;
    const int hw = p % HW;

    const float f0 = flow[(size_t)(b * 2) * HW + hw];
    const float f1 = flow[(size_t)(b * 2 + 1) * HW + hw];

    f32x16 a2a, a2b;
#pragma unroll
    for (int j = 0; j < 16; ++j) { a2a[j] = 0.f; a2b[j] = 0.f; }

    for (int c = 0; c < 64; ++c) {
        const float w0 = ws[OFF_WF1 + 2 * c];
        const float w1 = ws[OFF_WF1 + 2 * c + 1];
        float v  = fmaf(f0, w0, fmaf(f1, w1, bf1[c]));
        float r  = fmaxf(v, 0.f);
        float af = AS_ * fminf(rintf(r / AS_), 127.f);
        const float* w2 = ws + OFF_WF2 + c * 32;
#pragma unroll
        for (int j = 0; j < 16; ++j) {
            a2a[j] = fmaf(af, w2[j],      a2a[j]);
            a2b[j] = fmaf(af, w2[16 + j], a2b[j]);
        }
    }

    signed char* op = cfq + (size_t)b * 128 * HW + (size_t)96 * HW + hw;
#define FLOEPI(ACC, BASE)                                                        \
    _Pragma("unroll")                                                            \
    for (int j = 0; j < 16; ++j) {                                               \
        const int o = (BASE) + j;                                                \
        float v  = ACC[j] + bf2[o];                                              \
        float aq = AS_ * clip127(rintf(v / AS_));                                \
        float r  = fmaxf(aq, 0.f);                                               \
        float kk = fminf(rintf(r * 32.f), 127.f);                                \
        float cf = kk * FS_;                                                     \
        float q8 = clip127(rintf(cf / AS_));                                     \
        op[(size_t)o * HW] = (signed char)(int)q8;                               \
    }
    FLOEPI(a2a, 0) FLOEPI(a2b, 16)
#undef FLOEPI
}

// ---------------- kernel 2: depthwise 3x3 (VALU, exact) + pointwise via MFMA ----------------
#define STG_STRIDE 44
__global__ __launch_bounds__(256) void k2_dwpw(
    const float* __restrict__ flow, const float* __restrict__ bd,
    const float* __restrict__ bp,   const float* __restrict__ ws,
    const signed char* __restrict__ cfq, float* __restrict__ out)
{
    __shared__ signed char stage[4 * 128 * STG_STRIDE];   // [row][c][44]
    __shared__ unsigned short afrag[64 * 136];            // [pix][136] bf16 codes

    const int tid = threadIdx.x;
    const int bid = blockIdx.x;
    const int b   = bid / 300;          // 60 row-tiles * 5 col-tiles
    const int rem = bid % 300;
    const int h0  = (rem / 5) * 2;
    const int w0  = (rem % 5) * 32;

    for (int j = tid; j < 5120; j += 256) {
        const int i   = j % 10;
        const int c   = (j / 10) % 128;
        const int row = j / 1280;
        const int h   = h0 - 1 + row;
        const int wb  = w0 - 4 + 4 * i;
        unsigned int v = 0u;
        if (h >= 0 && h < HH && wb >= 0 && wb <= WW - 4)
            v = *(const unsigned int*)(cfq + ((size_t)(b * 128 + c) * HW + (size_t)h * WW + wb));
        *(unsigned int*)(stage + (row * 128 + c) * STG_STRIDE + i * 4) = v;
    }
    __syncthreads();

    const int c0 = tid & 63;
    const int pg = tid >> 6;
    const float sd = ws[0], sp = ws[1];
    const float ASsd = AS_ * sd;

    float wd0[9], wd1[9];
#pragma unroll
    for (int t9 = 0; t9 < 9; ++t9) {
        wd0[t9] = ws[OFF_WD + c0 * 9 + t9];
        wd1[t9] = ws[OFF_WD + (c0 + 64) * 9 + t9];
    }
    const float bd0 = bd[c0], bd1 = bd[c0 + 64];

#pragma unroll
    for (int pp = 0; pp < 16; ++pp) {
        const int pix = pg * 16 + pp;
        const int r   = pix >> 5;
        const int col = pix & 31;
        float s0 = 0.f, s1 = 0.f;
#pragma unroll
        for (int dy = 0; dy < 3; ++dy) {
            const int rb = (r + dy) * 128;
            const int xb = 3 + col;
#pragma unroll
            for (int dd = 0; dd < 3; ++dd) {
                s0 = fmaf((float)stage[(rb + c0     ) * STG_STRIDE + xb + dd], wd0[dy * 3 + dd], s0);
                s1 = fmaf((float)stage[(rb + c0 + 64) * STG_STRIDE + xb + dd], wd1[dy * 3 + dd], s1);
            }
        }
        const float q0 = clip127(rintf(fmaf(ASsd, s0, bd0) / AS_));
        const float q1 = clip127(rintf(fmaf(ASsd, s1, bd1) / AS_));
        afrag[pix * 136 + c0]      = f2bf(q0);
        afrag[pix * 136 + c0 + 64] = f2bf(q1);
    }
    __syncthreads();

    const int wv = tid >> 6;
    const int l  = tid & 63;
    const unsigned short* A = afrag + (size_t)(wv * 16 + (l & 15)) * 136 + ((l >> 4) << 3);
    const short8* Bfr = (const short8*)((const unsigned short*)ws + OFF_WPQ_US);

    f32x4 pc0 = {0.f,0.f,0.f,0.f}, pc1 = pc0, pc2 = pc0, pc3 = pc0, pc4 = pc0;

#define PTSTEP(ACC, KT, NT)                                                      \
    {   short8 bq = Bfr[((KT) * 5 + (NT)) * 64 + l];                             \
        ACC = __builtin_amdgcn_mfma_f32_16x16x32_bf16(a_, bq, ACC, 0, 0, 0);     }
#pragma unroll
    for (int kt = 0; kt < 4; ++kt) {
        short8 a_ = *(const short8*)(A + kt * 32);
        PTSTEP(pc0, kt, 0) PTSTEP(pc1, kt, 1) PTSTEP(pc2, kt, 2)
        PTSTEP(pc3, kt, 3) PTSTEP(pc4, kt, 4)
    }
#undef PTSTEP

    const float ASsp = AS_ * sp;
    float* ob = out + (size_t)b * 82 * HW;

#define PEPI(ACC, NT)                                                            \
    {   const int o = (NT) * 16 + (l & 15);                                      \
        const float bias = bp[o];                                                \
        _Pragma("unroll")                                                        \
        for (int i = 0; i < 4; ++i) {                                            \
            const int pix = wv * 16 + ((l >> 4) << 2) + i;                       \
            const int hw  = (h0 + (pix >> 5)) * WW + w0 + (pix & 31);            \
            float v = fmaf(ASsp, ACC[i], bias);                                  \
            float r = fmaxf(v, 0.f);                                             \
            float k = fminf(rintf(r * 32.f), 127.f);                             \
            ob[(size_t)o * HW + hw] = k * FS_;                                   \
        }                                                                        }
    PEPI(pc0, 0) PEPI(pc1, 1) PEPI(pc2, 2) PEPI(pc3, 3) PEPI(pc4, 4)
#undef PEPI

    if (tid < 128) {
        const int ch  = tid >> 6;
        const int pix = tid & 63;
        const int hw  = (h0 + (pix >> 5)) * WW + w0 + (pix & 31);
        const float f = flow[(size_t)(b * 2 + ch) * HW + hw];
        const float k = clip127(rintf(f * 32.f));
        ob[(size_t)(80 + ch) * HW + hw] = k * FS_;
    }
}

// ---------------- launcher ----------------
extern "C" void kernel_launch(void* const* d_in, const int* in_sizes, int n_in,
                              void* d_out, int out_size, void* d_ws, size_t ws_size,
                              hipStream_t stream) {
    const float* flow = (const float*)d_in[0];
    const float* corr = (const float*)d_in[1];
    const float* Wc1  = (const float*)d_in[2];
    const float* bc1  = (const float*)d_in[3];
    const float* Wf1  = (const float*)d_in[4];
    const float* bf1  = (const float*)d_in[5];
    const float* Wf2  = (const float*)d_in[6];
    const float* bf2  = (const float*)d_in[7];
    const float* Wd   = (const float*)d_in[8];
    const float* bd   = (const float*)d_in[9];
    const float* Wp   = (const float*)d_in[10];
    const float* bp   = (const float*)d_in[11];

    float* ws = (float*)d_ws;
    signed char* cfq = (signed char*)d_ws + CFQ_BYTE_OFF;
    float* out = (float*)d_out;

    quant_weights<<<5, 256, 0, stream>>>(Wc1, Wf1, Wf2, Wd, Wp, ws);
    k1_convc1<<<NPIX / 128, 256, 0, stream>>>(corr, bc1, ws, cfq);
    k1_flo<<<NPIX / 256, 256, 0, stream>>>(flow, bf1, bf2, ws, cfq);
    k2_dwpw<<<2400, 256, 0, stream>>>(flow, bd, bp, ws, cfq, out);
}